// Round 2
// baseline (869.427 us; speedup 1.0000x reference)
//
#include <hip/hip_runtime.h>
#include <hip/hip_bf16.h>
#include <math.h>

// Problem constants (from reference)
#define T_TOK 8192            // B*S = 4*2048
#define HID   1024
#define NE    8
#define TOPKN 2
#define INTER 1408
#define NROWS (T_TOK*TOPKN)   // 16384 routed (token,expert) rows

typedef __attribute__((ext_vector_type(8))) __bf16 bf16x8;
typedef __attribute__((ext_vector_type(4))) float f32x4;
typedef __attribute__((ext_vector_type(4))) unsigned int u32x4;

__device__ __forceinline__ unsigned short f2bf(float f) {
    unsigned int u = __builtin_bit_cast(unsigned int, f);
    unsigned int lsb = (u >> 16) & 1u;
    u += 0x7fffu + lsb;            // round-to-nearest-even
    return (unsigned short)(u >> 16);
}

// async global->LDS, 16B per lane. Global addr is per-lane; LDS dest is
// wave-uniform base + lane*16 (m97 pattern).
__device__ __forceinline__ void gl2lds16(const void* g, void* l) {
    __builtin_amdgcn_global_load_lds(
        (const __attribute__((address_space(1))) unsigned int*)g,
        (__attribute__((address_space(3))) unsigned int*)l, 16, 0, 0);
}

// ---------------------------------------------------------------- meta zero
__global__ void moe_zero_meta(int* counts, int* cursor) {
    int i = threadIdx.x;
    if (i < NE) { counts[i] = 0; cursor[i] = 0; }
}

// ---------------------------------------------------------------- router
__global__ __launch_bounds__(256) void moe_router(
    const float* __restrict__ x, const float* __restrict__ gate_w,
    unsigned short* __restrict__ xb, float* __restrict__ logits_out,
    int* __restrict__ topk_idx, float* __restrict__ topk_w,
    int* __restrict__ counts)
{
    __shared__ float gw[NE * HID];
    int tid = threadIdx.x;
    for (int i = tid; i < NE * HID / 4; i += 256)
        ((float4*)gw)[i] = ((const float4*)gate_w)[i];
    __syncthreads();

    int wave = tid >> 6, lane = tid & 63;
    int t = blockIdx.x * 4 + wave;
    const float* xrow = x + (size_t)t * HID;
    unsigned short* xbrow = xb + (size_t)t * HID;

    float acc[NE];
#pragma unroll
    for (int e = 0; e < NE; e++) acc[e] = 0.f;
#pragma unroll
    for (int j = 0; j < HID / 64; j++) {
        int h = j * 64 + lane;
        float xv = xrow[h];
        xbrow[h] = f2bf(xv);
#pragma unroll
        for (int e = 0; e < NE; e++) acc[e] += xv * gw[e * HID + h];
    }
#pragma unroll
    for (int e = 0; e < NE; e++) {
        float v = acc[e];
#pragma unroll
        for (int off = 32; off; off >>= 1) v += __shfl_xor(v, off, 64);
        acc[e] = v;
    }
    if (lane == 0) {
        float m = acc[0];
#pragma unroll
        for (int e = 1; e < NE; e++) m = fmaxf(m, acc[e]);
        float p[NE]; float s = 0.f;
#pragma unroll
        for (int e = 0; e < NE; e++) { p[e] = expf(acc[e] - m); s += p[e]; }
        float inv = 1.f / s;
#pragma unroll
        for (int e = 0; e < NE; e++) logits_out[(size_t)t * NE + e] = acc[e];
        int i0 = 0;
#pragma unroll
        for (int e = 1; e < NE; e++) if (p[e] > p[i0]) i0 = e;
        int i1 = (i0 == 0) ? 1 : 0;
#pragma unroll
        for (int e = 0; e < NE; e++) if (e != i0 && p[e] > p[i1]) i1 = e;
        topk_idx[2 * t]     = i0; topk_w[2 * t]     = p[i0] * inv;
        topk_idx[2 * t + 1] = i1; topk_w[2 * t + 1] = p[i1] * inv;
        atomicAdd(&counts[i0], 1);
        atomicAdd(&counts[i1], 1);
    }
}

// ---------------------------------------------------------------- scan
__global__ void moe_scan(const int* __restrict__ counts, int* __restrict__ offsets) {
    if (threadIdx.x == 0) {
        int s = 0;
        for (int e = 0; e < NE; e++) { offsets[e] = s; s += counts[e]; }
        offsets[NE] = s;
    }
}

// ---------------------------------------------------------------- scatter
__global__ __launch_bounds__(256) void moe_scatter(
    const int* __restrict__ topk_idx, const float* __restrict__ topk_w,
    const int* __restrict__ offsets, int* __restrict__ cursor,
    int* __restrict__ row_token, float* __restrict__ row_w,
    int* __restrict__ tok_rows)
{
    int t = blockIdx.x * 256 + threadIdx.x;
    if (t >= T_TOK) return;
#pragma unroll
    for (int k = 0; k < TOPKN; k++) {
        int e = topk_idx[2 * t + k];
        int pos = atomicAdd(&cursor[e], 1);
        int row = offsets[e] + pos;
        row_token[row] = t;
        row_w[row] = topk_w[2 * t + k];
        tok_rows[2 * t + k] = row;
    }
}

// ---------------------------------------------------------------- transpose+cast
// in: fp32 [NE][R_][C_]  ->  out: bf16 [NE][C_][R_]   (k-contiguous weights)
__global__ __launch_bounds__(256) void moe_transpose_cast(
    const float* __restrict__ in, unsigned short* __restrict__ out,
    int R_, int C_)
{
    __shared__ float tile[32][33];
    int e = blockIdx.z;
    const float* ine = in + (size_t)e * R_ * C_;
    unsigned short* oute = out + (size_t)e * R_ * C_;
    int c0 = blockIdx.x * 32, r0 = blockIdx.y * 32;
    int tx = threadIdx.x, ty = threadIdx.y;     // (32,8)
#pragma unroll
    for (int j = 0; j < 4; j++) {
        int r = r0 + ty + j * 8;
        tile[ty + j * 8][tx] = ine[(size_t)r * C_ + c0 + tx];
    }
    __syncthreads();
#pragma unroll
    for (int j = 0; j < 4; j++) {
        int c = c0 + ty + j * 8;
        oute[(size_t)c * R_ + r0 + tx] = f2bf(tile[tx][ty + j * 8]);
    }
}

// ---------------------------------------------------------------- grouped GEMM1
// 128 rows x 64 i-cols per block, computing BOTH g and u (SiLU pairing is
// wave-local). LDS layout chunk-major: chunk = q*ROWS + r, 16B each, matches
// global_load_lds lane order AND gives conflict-free ds_read_b128 frags.
__global__ __launch_bounds__(256) void moe_gemm1(
    const unsigned short* __restrict__ xb,
    const unsigned short* __restrict__ wg_t,   // [NE][INTER][HID]
    const unsigned short* __restrict__ wu_t,   // [NE][INTER][HID]
    const int* __restrict__ offsets, const int* __restrict__ row_token,
    unsigned short* __restrict__ h_buf)        // [NROWS][INTER]
{
    int e = blockIdx.z;
    int off = offsets[e], cnt = offsets[e + 1] - off;
    int row0 = blockIdx.y * 128;
    if (row0 >= cnt) return;
    int i0 = blockIdx.x * 64;

    __shared__ __align__(16) unsigned short As[8 * 128 * 8];  // 16 KB
    __shared__ __align__(16) unsigned short Bg[8 * 64 * 8];   // 8 KB
    __shared__ __align__(16) unsigned short Bu[8 * 64 * 8];   // 8 KB

    int tid = threadIdx.x, wave = tid >> 6, lane = tid & 63;
    int wm = wave & 1, wn = wave >> 1;
    int l16 = lane & 15, quad = lane >> 4;

    // each lane owns one A row for the whole block (gathered token row)
    int m_mine = wm * 64 + lane;
    int rg = row0 + m_mine;
    const unsigned short* aptr = xb;                       // safe garbage for OOB rows
    if (rg < cnt) aptr = xb + (size_t)row_token[off + rg] * HID;
    const unsigned short* bgp = wg_t + (size_t)e * INTER * HID + (size_t)(i0 + lane) * HID;
    const unsigned short* bup = wu_t + (size_t)e * INTER * HID + (size_t)(i0 + lane) * HID;

    f32x4 accg[4][2], accu[4][2];
#pragma unroll
    for (int mi = 0; mi < 4; mi++)
#pragma unroll
        for (int ni = 0; ni < 2; ni++) {
            accg[mi][ni] = {0.f, 0.f, 0.f, 0.f};
            accu[mi][ni] = {0.f, 0.f, 0.f, 0.f};
        }

    for (int k0 = 0; k0 < HID; k0 += 64) {
        // stage A: 1024 chunks, lane's m fixed, q = 2r + wn
#pragma unroll
        for (int r = 0; r < 4; r++) {
            int q = 2 * r + wn;
            gl2lds16(aptr + k0 + q * 8, &As[(q * 128 + wm * 64) * 8]);
        }
        // stage Bg/Bu: 512 chunks each, lane's n fixed, q = 4r + wave
#pragma unroll
        for (int r = 0; r < 2; r++) {
            int q = 4 * r + wave;
            gl2lds16(bgp + k0 + q * 8, &Bg[q * 64 * 8]);
            gl2lds16(bup + k0 + q * 8, &Bu[q * 64 * 8]);
        }
        __syncthreads();
#pragma unroll
        for (int kk8 = 0; kk8 < 8; kk8 += 4) {
            int q = kk8 + quad;
            bf16x8 a[4], bg[2], bu[2];
#pragma unroll
            for (int mi = 0; mi < 4; mi++)
                a[mi] = *(const bf16x8*)&As[(q * 128 + wm * 64 + mi * 16 + l16) * 8];
#pragma unroll
            for (int ni = 0; ni < 2; ni++) {
                bg[ni] = *(const bf16x8*)&Bg[(q * 64 + wn * 32 + ni * 16 + l16) * 8];
                bu[ni] = *(const bf16x8*)&Bu[(q * 64 + wn * 32 + ni * 16 + l16) * 8];
            }
#pragma unroll
            for (int mi = 0; mi < 4; mi++)
#pragma unroll
                for (int ni = 0; ni < 2; ni++) {
                    accg[mi][ni] = __builtin_amdgcn_mfma_f32_16x16x32_bf16(a[mi], bg[ni], accg[mi][ni], 0, 0, 0);
                    accu[mi][ni] = __builtin_amdgcn_mfma_f32_16x16x32_bf16(a[mi], bu[ni], accu[mi][ni], 0, 0, 0);
                }
        }
        __syncthreads();
    }
    // epilogue: silu(g)*u -> bf16  (C/D: col=lane&15, row=quad*4+reg)
#pragma unroll
    for (int mi = 0; mi < 4; mi++)
#pragma unroll
        for (int ni = 0; ni < 2; ni++)
#pragma unroll
            for (int r = 0; r < 4; r++) {
                int ml = wm * 64 + mi * 16 + quad * 4 + r;
                int row = row0 + ml;
                if (row < cnt) {
                    float g = accg[mi][ni][r], u = accu[mi][ni][r];
                    float hv = (g / (1.f + expf(-g))) * u;
                    h_buf[(size_t)(off + row) * INTER + i0 + wn * 32 + ni * 16 + l16] = f2bf(hv);
                }
            }
}

// ---------------------------------------------------------------- grouped GEMM2
// classic m97 128x128, per-wave 64x64.
__global__ __launch_bounds__(256) void moe_gemm2(
    const unsigned short* __restrict__ h_buf,  // [NROWS][INTER]
    const unsigned short* __restrict__ wd_t,   // [NE][HID][INTER]
    const int* __restrict__ offsets, const float* __restrict__ row_w,
    unsigned short* __restrict__ y_buf)        // [NROWS][HID]
{
    int e = blockIdx.z;
    int off = offsets[e], cnt = offsets[e + 1] - off;
    int row0 = blockIdx.y * 128;
    if (row0 >= cnt) return;
    int h0 = blockIdx.x * 128;

    __shared__ __align__(16) unsigned short As[8 * 128 * 8];  // 16 KB
    __shared__ __align__(16) unsigned short Bs[8 * 128 * 8];  // 16 KB

    int tid = threadIdx.x, wave = tid >> 6, lane = tid & 63;
    int wm = wave & 1, wn = wave >> 1;
    int l16 = lane & 15, quad = lane >> 4;

    int m_mine = wm * 64 + lane;
    int rg = row0 + m_mine;
    const unsigned short* aptr = h_buf + (size_t)(off + ((rg < cnt) ? rg : 0)) * INTER;
    const unsigned short* bptr = wd_t + (size_t)e * HID * INTER + (size_t)(h0 + wm * 64 + lane) * INTER;

    f32x4 acc[4][4];
#pragma unroll
    for (int mi = 0; mi < 4; mi++)
#pragma unroll
        for (int ni = 0; ni < 4; ni++) acc[mi][ni] = {0.f, 0.f, 0.f, 0.f};

    for (int k0 = 0; k0 < INTER; k0 += 64) {
#pragma unroll
        for (int r = 0; r < 4; r++) {
            int q = 2 * r + wn;
            gl2lds16(aptr + k0 + q * 8, &As[(q * 128 + wm * 64) * 8]);
            gl2lds16(bptr + k0 + q * 8, &Bs[(q * 128 + wm * 64) * 8]);
        }
        __syncthreads();
#pragma unroll
        for (int kk8 = 0; kk8 < 8; kk8 += 4) {
            int q = kk8 + quad;
            bf16x8 a[4], b[4];
#pragma unroll
            for (int mi = 0; mi < 4; mi++)
                a[mi] = *(const bf16x8*)&As[(q * 128 + wm * 64 + mi * 16 + l16) * 8];
#pragma unroll
            for (int ni = 0; ni < 4; ni++)
                b[ni] = *(const bf16x8*)&Bs[(q * 128 + wn * 64 + ni * 16 + l16) * 8];
#pragma unroll
            for (int mi = 0; mi < 4; mi++)
#pragma unroll
                for (int ni = 0; ni < 4; ni++)
                    acc[mi][ni] = __builtin_amdgcn_mfma_f32_16x16x32_bf16(a[mi], b[ni], acc[mi][ni], 0, 0, 0);
        }
        __syncthreads();
    }
#pragma unroll
    for (int mi = 0; mi < 4; mi++)
#pragma unroll
        for (int ni = 0; ni < 4; ni++)
#pragma unroll
            for (int r = 0; r < 4; r++) {
                int ml = wm * 64 + mi * 16 + quad * 4 + r;
                int row = row0 + ml;
                if (row < cnt) {
                    float w = row_w[off + row];
                    y_buf[(size_t)(off + row) * HID + h0 + wn * 64 + ni * 16 + l16] =
                        f2bf(acc[mi][ni][r] * w);
                }
            }
}

// ---------------------------------------------------------------- combine
__global__ __launch_bounds__(256) void moe_combine(
    const unsigned short* __restrict__ y_buf, const int* __restrict__ tok_rows,
    float* __restrict__ out)
{
    int gid = blockIdx.x * 256 + threadIdx.x;   // T*H/8 threads
    int t = gid >> 7;
    int c = gid & 127;
    u32x4 a = *(const u32x4*)(y_buf + (size_t)tok_rows[2 * t]     * HID + c * 8);
    u32x4 b = *(const u32x4*)(y_buf + (size_t)tok_rows[2 * t + 1] * HID + c * 8);
    float res[8];
#pragma unroll
    for (int j = 0; j < 4; j++) {
        unsigned int wa = a[j], wb = b[j];
        res[2 * j]     = __builtin_bit_cast(float, wa << 16)
                       + __builtin_bit_cast(float, wb << 16);
        res[2 * j + 1] = __builtin_bit_cast(float, wa & 0xffff0000u)
                       + __builtin_bit_cast(float, wb & 0xffff0000u);
    }
    float* o = out + (size_t)t * HID + c * 8;
    *(float4*)(o)     = make_float4(res[0], res[1], res[2], res[3]);
    *(float4*)(o + 4) = make_float4(res[4], res[5], res[6], res[7]);
}

// ---------------------------------------------------------------- launch
extern "C" void kernel_launch(void* const* d_in, const int* in_sizes, int n_in,
                              void* d_out, int out_size, void* d_ws, size_t ws_size,
                              hipStream_t stream)
{
    const float* x      = (const float*)d_in[0];
    const float* gate_w = (const float*)d_in[1];
    const float* w_gate = (const float*)d_in[2];
    const float* w_up   = (const float*)d_in[3];
    const float* w_down = (const float*)d_in[4];
    float* out = (float*)d_out;                    // final [T,H] ++ logits [T,E]
    float* logits_out = out + (size_t)T_TOK * HID;

    char* ws = (char*)d_ws;
    int*   counts    = (int*)(ws + 0);
    int*   cursor    = (int*)(ws + 32);
    int*   offsets   = (int*)(ws + 64);
    int*   topk_idx  = (int*)(ws + 256);
    float* topk_w    = (float*)(ws + 256 + 65536);
    int*   row_token = (int*)(ws + 256 + 2 * 65536);
    float* row_w     = (float*)(ws + 256 + 3 * 65536);
    int*   tok_rows  = (int*)(ws + 256 + 4 * 65536);
    size_t o = 256 + 5 * (size_t)65536 + 65280;
    unsigned short* xb   = (unsigned short*)(ws + o); o += (size_t)T_TOK * HID * 2;
    unsigned short* wg_t = (unsigned short*)(ws + o); o += (size_t)NE * INTER * HID * 2;
    unsigned short* wu_t = (unsigned short*)(ws + o); o += (size_t)NE * INTER * HID * 2;
    unsigned short* wd_t = (unsigned short*)(ws + o); o += (size_t)NE * HID * INTER * 2;
    unsigned short* h_buf = (unsigned short*)(ws + o); o += (size_t)NROWS * INTER * 2;
    unsigned short* y_buf = (unsigned short*)(ws + o); o += (size_t)NROWS * HID * 2;

    moe_zero_meta<<<1, 64, 0, stream>>>(counts, cursor);
    moe_router<<<T_TOK / 4, 256, 0, stream>>>(x, gate_w, xb, logits_out,
                                              topk_idx, topk_w, counts);
    moe_scan<<<1, 64, 0, stream>>>(counts, offsets);
    moe_scatter<<<T_TOK / 256, 256, 0, stream>>>(topk_idx, topk_w, offsets, cursor,
                                                 row_token, row_w, tok_rows);
    dim3 tb(32, 8, 1);
    moe_transpose_cast<<<dim3(INTER / 32, HID / 32, NE), tb, 0, stream>>>(w_gate, wg_t, HID, INTER);
    moe_transpose_cast<<<dim3(INTER / 32, HID / 32, NE), tb, 0, stream>>>(w_up,   wu_t, HID, INTER);
    moe_transpose_cast<<<dim3(HID / 32, INTER / 32, NE), tb, 0, stream>>>(w_down, wd_t, INTER, HID);

    moe_gemm1<<<dim3(INTER / 64, NROWS / 128, NE), 256, 0, stream>>>(
        xb, wg_t, wu_t, offsets, row_token, h_buf);
    moe_gemm2<<<dim3(HID / 128, NROWS / 128, NE), 256, 0, stream>>>(
        h_buf, wd_t, offsets, row_w, y_buf);
    moe_combine<<<(T_TOK * HID / 8) / 256, 256, 0, stream>>>(y_buf, tok_rows, out);
}

// Round 3
// 724.541 us; speedup vs baseline: 1.2000x; 1.2000x over previous
//
#include <hip/hip_runtime.h>
#include <hip/hip_bf16.h>
#include <math.h>

// Problem constants (from reference)
#define T_TOK 8192            // B*S = 4*2048
#define HID   1024
#define NE    8
#define TOPKN 2
#define INTER 1408
#define NROWS (T_TOK*TOPKN)   // 16384 routed (token,expert) rows
#define MAXWL 144             // max row-block worklist entries (128+8 rounded)

typedef __attribute__((ext_vector_type(8))) __bf16 bf16x8;
typedef __attribute__((ext_vector_type(4))) float f32x4;
typedef __attribute__((ext_vector_type(4))) unsigned int u32x4;

__device__ __forceinline__ unsigned short f2bf(float f) {
    unsigned int u = __builtin_bit_cast(unsigned int, f);
    unsigned int lsb = (u >> 16) & 1u;
    u += 0x7fffu + lsb;            // round-to-nearest-even
    return (unsigned short)(u >> 16);
}

// async global->LDS, 16B per lane. Global addr per-lane (must be coalesced for
// speed); LDS dest is wave-uniform base + lane*16 (m97 pattern).
__device__ __forceinline__ void gl2lds16(const void* g, void* l) {
    __builtin_amdgcn_global_load_lds(
        (const __attribute__((address_space(1))) unsigned int*)g,
        (__attribute__((address_space(3))) unsigned int*)l, 16, 0, 0);
}

// ---------------------------------------------------------------- meta zero
__global__ void moe_zero_meta(int* counts, int* cursor) {
    int i = threadIdx.x;
    if (i < NE) { counts[i] = 0; cursor[i] = 0; }
}

// ---------------------------------------------------------------- router
__global__ __launch_bounds__(256) void moe_router(
    const float* __restrict__ x, const float* __restrict__ gate_w,
    unsigned short* __restrict__ xb, float* __restrict__ logits_out,
    int* __restrict__ topk_idx, float* __restrict__ topk_w,
    int* __restrict__ counts)
{
    __shared__ float gw[NE * HID];
    int tid = threadIdx.x;
    for (int i = tid; i < NE * HID / 4; i += 256)
        ((float4*)gw)[i] = ((const float4*)gate_w)[i];
    __syncthreads();

    int wave = tid >> 6, lane = tid & 63;
    int t = blockIdx.x * 4 + wave;
    const float* xrow = x + (size_t)t * HID;
    unsigned short* xbrow = xb + (size_t)t * HID;

    float acc[NE];
#pragma unroll
    for (int e = 0; e < NE; e++) acc[e] = 0.f;
#pragma unroll
    for (int j = 0; j < HID / 64; j++) {
        int h = j * 64 + lane;
        float xv = xrow[h];
        xbrow[h] = f2bf(xv);
#pragma unroll
        for (int e = 0; e < NE; e++) acc[e] += xv * gw[e * HID + h];
    }
#pragma unroll
    for (int e = 0; e < NE; e++) {
        float v = acc[e];
#pragma unroll
        for (int off = 32; off; off >>= 1) v += __shfl_xor(v, off, 64);
        acc[e] = v;
    }
    if (lane == 0) {
        float m = acc[0];
#pragma unroll
        for (int e = 1; e < NE; e++) m = fmaxf(m, acc[e]);
        float p[NE]; float s = 0.f;
#pragma unroll
        for (int e = 0; e < NE; e++) { p[e] = expf(acc[e] - m); s += p[e]; }
        float inv = 1.f / s;
#pragma unroll
        for (int e = 0; e < NE; e++) logits_out[(size_t)t * NE + e] = acc[e];
        int i0 = 0;
#pragma unroll
        for (int e = 1; e < NE; e++) if (p[e] > p[i0]) i0 = e;
        int i1 = (i0 == 0) ? 1 : 0;
#pragma unroll
        for (int e = 0; e < NE; e++) if (e != i0 && p[e] > p[i1]) i1 = e;
        topk_idx[2 * t]     = i0; topk_w[2 * t]     = p[i0] * inv;
        topk_idx[2 * t + 1] = i1; topk_w[2 * t + 1] = p[i1] * inv;
        atomicAdd(&counts[i0], 1);
        atomicAdd(&counts[i1], 1);
    }
}

// ---------------------------------------------------------------- scan + worklist
__global__ void moe_scan(const int* __restrict__ counts, int* __restrict__ offsets,
                         int* __restrict__ wl, int* __restrict__ n_wl) {
    if (threadIdx.x == 0) {
        int s = 0;
        for (int e = 0; e < NE; e++) { offsets[e] = s; s += counts[e]; }
        offsets[NE] = s;
        int n = 0;
        for (int e = 0; e < NE; e++)
            for (int r0 = 0; r0 < counts[e]; r0 += 128)
                wl[n++] = (e << 24) | r0;
        *n_wl = n;
    }
}

// ---------------------------------------------------------------- scatter
__global__ __launch_bounds__(256) void moe_scatter(
    const int* __restrict__ topk_idx, const float* __restrict__ topk_w,
    const int* __restrict__ offsets, int* __restrict__ cursor,
    int* __restrict__ row_token, float* __restrict__ row_w,
    int* __restrict__ tok_rows)
{
    int t = blockIdx.x * 256 + threadIdx.x;
    if (t >= T_TOK) return;
#pragma unroll
    for (int k = 0; k < TOPKN; k++) {
        int e = topk_idx[2 * t + k];
        int pos = atomicAdd(&cursor[e], 1);
        int row = offsets[e] + pos;
        row_token[row] = t;
        row_w[row] = topk_w[2 * t + k];
        tok_rows[2 * t + k] = row;
    }
}

// ---------------------------------------------------------------- transpose+cast
// in: fp32 [NE][R_][C_]  ->  out: bf16 [NE][C_][R_]   (k-contiguous weights)
__global__ __launch_bounds__(256) void moe_transpose_cast(
    const float* __restrict__ in, unsigned short* __restrict__ out,
    int R_, int C_)
{
    __shared__ float tile[32][33];
    int e = blockIdx.z;
    const float* ine = in + (size_t)e * R_ * C_;
    unsigned short* oute = out + (size_t)e * R_ * C_;
    int c0 = blockIdx.x * 32, r0 = blockIdx.y * 32;
    int tx = threadIdx.x, ty = threadIdx.y;     // (32,8)
#pragma unroll
    for (int j = 0; j < 4; j++) {
        int r = r0 + ty + j * 8;
        tile[ty + j * 8][tx] = ine[(size_t)r * C_ + c0 + tx];
    }
    __syncthreads();
#pragma unroll
    for (int j = 0; j < 4; j++) {
        int c = c0 + ty + j * 8;
        oute[(size_t)c * R_ + r0 + tx] = f2bf(tile[tx][ty + j * 8]);
    }
}

// ---------------------------------------------------------------- grouped GEMM1
// 128 rows x 64 i-cols per block, computes BOTH g and u (SiLU pairing wave-local).
// LDS row-major [row][chunk], chunk c of row r holds logical k-chunk q = c^(r&7)
// (XOR swizzle): staging is lane-contiguous AND coalesced; frag ds_read_b128 is
// 2-way bank aliased (free).
__global__ __launch_bounds__(256) void moe_gemm1(
    const unsigned short* __restrict__ xb,
    const unsigned short* __restrict__ wg_t,   // [NE][INTER][HID]
    const unsigned short* __restrict__ wu_t,   // [NE][INTER][HID]
    const int* __restrict__ offsets, const int* __restrict__ row_token,
    const int* __restrict__ wl, const int* __restrict__ n_wl,
    unsigned short* __restrict__ h_buf)        // [NROWS][INTER]
{
    if ((int)blockIdx.y >= *n_wl) return;
    int wle = wl[blockIdx.y];
    int e = wle >> 24, row0 = wle & 0xffffff;
    int off = offsets[e], cnt = offsets[e + 1] - off;
    int i0 = blockIdx.x * 64;

    __shared__ __align__(16) unsigned short As[128 * 64];  // 16 KB: [row][8 chunks]
    __shared__ __align__(16) unsigned short Bg[64 * 64];   // 8 KB
    __shared__ __align__(16) unsigned short Bu[64 * 64];   // 8 KB

    int tid = threadIdx.x, wave = tid >> 6, lane = tid & 63;
    int wm = wave & 1, wn = wave >> 1;
    int l16 = lane & 15, quad = lane >> 4;
    int r_ = lane >> 3, c_ = lane & 7;     // staging: 8 rows x 8 chunks per wave-instr
    int sw = l16 & 7;                      // frag-read xor swizzle

    // per-lane staging source pointers (constant across K-loop)
    const unsigned short* asrc[4];
#pragma unroll
    for (int it = 0; it < 4; it++) {
        int rloc = it * 32 + wave * 8 + r_;
        int rg = row0 + rloc;
        int tok = row_token[off + ((rg < cnt) ? rg : 0)];
        asrc[it] = xb + (size_t)tok * HID + (c_ ^ (rloc & 7)) * 8;
    }
    const unsigned short* bgsrc[2];
    const unsigned short* busrc[2];
#pragma unroll
    for (int it = 0; it < 2; it++) {
        int rloc = it * 32 + wave * 8 + r_;
        size_t boff = (size_t)e * INTER * HID + (size_t)(i0 + rloc) * HID + (c_ ^ (rloc & 7)) * 8;
        bgsrc[it] = wg_t + boff;
        busrc[it] = wu_t + boff;
    }

    f32x4 accg[4][2], accu[4][2];
#pragma unroll
    for (int mi = 0; mi < 4; mi++)
#pragma unroll
        for (int ni = 0; ni < 2; ni++) {
            accg[mi][ni] = {0.f, 0.f, 0.f, 0.f};
            accu[mi][ni] = {0.f, 0.f, 0.f, 0.f};
        }

    for (int k0 = 0; k0 < HID; k0 += 64) {
#pragma unroll
        for (int it = 0; it < 4; it++)
            gl2lds16(asrc[it] + k0, &As[(it * 32 + wave * 8) * 64]);
#pragma unroll
        for (int it = 0; it < 2; it++) {
            gl2lds16(bgsrc[it] + k0, &Bg[(it * 32 + wave * 8) * 64]);
            gl2lds16(busrc[it] + k0, &Bu[(it * 32 + wave * 8) * 64]);
        }
        __syncthreads();
#pragma unroll
        for (int kk8 = 0; kk8 < 8; kk8 += 4) {
            int q = kk8 + quad;
            int qs = (q ^ sw) * 8;
            bf16x8 a[4], bg[2], bu[2];
#pragma unroll
            for (int mi = 0; mi < 4; mi++)
                a[mi] = *(const bf16x8*)&As[(wm * 64 + mi * 16 + l16) * 64 + qs];
#pragma unroll
            for (int ni = 0; ni < 2; ni++) {
                bg[ni] = *(const bf16x8*)&Bg[(wn * 32 + ni * 16 + l16) * 64 + qs];
                bu[ni] = *(const bf16x8*)&Bu[(wn * 32 + ni * 16 + l16) * 64 + qs];
            }
#pragma unroll
            for (int mi = 0; mi < 4; mi++)
#pragma unroll
                for (int ni = 0; ni < 2; ni++) {
                    accg[mi][ni] = __builtin_amdgcn_mfma_f32_16x16x32_bf16(a[mi], bg[ni], accg[mi][ni], 0, 0, 0);
                    accu[mi][ni] = __builtin_amdgcn_mfma_f32_16x16x32_bf16(a[mi], bu[ni], accu[mi][ni], 0, 0, 0);
                }
        }
        __syncthreads();
    }
    // epilogue: silu(g)*u -> bf16  (C/D: col=lane&15, row=quad*4+reg)
#pragma unroll
    for (int mi = 0; mi < 4; mi++)
#pragma unroll
        for (int ni = 0; ni < 2; ni++)
#pragma unroll
            for (int r = 0; r < 4; r++) {
                int ml = wm * 64 + mi * 16 + quad * 4 + r;
                int row = row0 + ml;
                if (row < cnt) {
                    float g = accg[mi][ni][r], u = accu[mi][ni][r];
                    float hv = (g / (1.f + expf(-g))) * u;
                    h_buf[(size_t)(off + row) * INTER + i0 + wn * 32 + ni * 16 + l16] = f2bf(hv);
                }
            }
}

// ---------------------------------------------------------------- grouped GEMM2
// m97-style 128x128, per-wave 64x64, same XOR-swizzle staging.
__global__ __launch_bounds__(256) void moe_gemm2(
    const unsigned short* __restrict__ h_buf,  // [NROWS][INTER]
    const unsigned short* __restrict__ wd_t,   // [NE][HID][INTER]
    const int* __restrict__ offsets, const float* __restrict__ row_w,
    const int* __restrict__ wl, const int* __restrict__ n_wl,
    unsigned short* __restrict__ y_buf)        // [NROWS][HID]
{
    if ((int)blockIdx.y >= *n_wl) return;
    int wle = wl[blockIdx.y];
    int e = wle >> 24, row0 = wle & 0xffffff;
    int off = offsets[e], cnt = offsets[e + 1] - off;
    int h0 = blockIdx.x * 128;

    __shared__ __align__(16) unsigned short As[128 * 64];  // 16 KB
    __shared__ __align__(16) unsigned short Bs[128 * 64];  // 16 KB

    int tid = threadIdx.x, wave = tid >> 6, lane = tid & 63;
    int wm = wave & 1, wn = wave >> 1;
    int l16 = lane & 15, quad = lane >> 4;
    int r_ = lane >> 3, c_ = lane & 7;
    int sw = l16 & 7;

    const unsigned short* asrc[4];
    const unsigned short* bsrc[4];
#pragma unroll
    for (int it = 0; it < 4; it++) {
        int rloc = it * 32 + wave * 8 + r_;
        int rg = row0 + rloc;
        asrc[it] = h_buf + (size_t)(off + ((rg < cnt) ? rg : 0)) * INTER + (c_ ^ (rloc & 7)) * 8;
        bsrc[it] = wd_t + (size_t)e * HID * INTER + (size_t)(h0 + rloc) * INTER + (c_ ^ (rloc & 7)) * 8;
    }

    f32x4 acc[4][4];
#pragma unroll
    for (int mi = 0; mi < 4; mi++)
#pragma unroll
        for (int ni = 0; ni < 4; ni++) acc[mi][ni] = {0.f, 0.f, 0.f, 0.f};

    for (int k0 = 0; k0 < INTER; k0 += 64) {
#pragma unroll
        for (int it = 0; it < 4; it++) {
            gl2lds16(asrc[it] + k0, &As[(it * 32 + wave * 8) * 64]);
            gl2lds16(bsrc[it] + k0, &Bs[(it * 32 + wave * 8) * 64]);
        }
        __syncthreads();
#pragma unroll
        for (int kk8 = 0; kk8 < 8; kk8 += 4) {
            int q = kk8 + quad;
            int qs = (q ^ sw) * 8;
            bf16x8 a[4], b[4];
#pragma unroll
            for (int mi = 0; mi < 4; mi++)
                a[mi] = *(const bf16x8*)&As[(wm * 64 + mi * 16 + l16) * 64 + qs];
#pragma unroll
            for (int ni = 0; ni < 4; ni++)
                b[ni] = *(const bf16x8*)&Bs[(wn * 64 + ni * 16 + l16) * 64 + qs];
#pragma unroll
            for (int mi = 0; mi < 4; mi++)
#pragma unroll
                for (int ni = 0; ni < 4; ni++)
                    acc[mi][ni] = __builtin_amdgcn_mfma_f32_16x16x32_bf16(a[mi], b[ni], acc[mi][ni], 0, 0, 0);
        }
        __syncthreads();
    }
#pragma unroll
    for (int mi = 0; mi < 4; mi++)
#pragma unroll
        for (int ni = 0; ni < 4; ni++)
#pragma unroll
            for (int r = 0; r < 4; r++) {
                int ml = wm * 64 + mi * 16 + quad * 4 + r;
                int row = row0 + ml;
                if (row < cnt) {
                    float w = row_w[off + row];
                    y_buf[(size_t)(off + row) * HID + h0 + wn * 64 + ni * 16 + l16] =
                        f2bf(acc[mi][ni][r] * w);
                }
            }
}

// ---------------------------------------------------------------- combine
__global__ __launch_bounds__(256) void moe_combine(
    const unsigned short* __restrict__ y_buf, const int* __restrict__ tok_rows,
    float* __restrict__ out)
{
    int gid = blockIdx.x * 256 + threadIdx.x;   // T*H/8 threads
    int t = gid >> 7;
    int c = gid & 127;
    u32x4 a = *(const u32x4*)(y_buf + (size_t)tok_rows[2 * t]     * HID + c * 8);
    u32x4 b = *(const u32x4*)(y_buf + (size_t)tok_rows[2 * t + 1] * HID + c * 8);
    float res[8];
#pragma unroll
    for (int j = 0; j < 4; j++) {
        unsigned int wa = a[j], wb = b[j];
        res[2 * j]     = __builtin_bit_cast(float, wa << 16)
                       + __builtin_bit_cast(float, wb << 16);
        res[2 * j + 1] = __builtin_bit_cast(float, wa & 0xffff0000u)
                       + __builtin_bit_cast(float, wb & 0xffff0000u);
    }
    float* o = out + (size_t)t * HID + c * 8;
    *(float4*)(o)     = make_float4(res[0], res[1], res[2], res[3]);
    *(float4*)(o + 4) = make_float4(res[4], res[5], res[6], res[7]);
}

// ---------------------------------------------------------------- launch
extern "C" void kernel_launch(void* const* d_in, const int* in_sizes, int n_in,
                              void* d_out, int out_size, void* d_ws, size_t ws_size,
                              hipStream_t stream)
{
    const float* x      = (const float*)d_in[0];
    const float* gate_w = (const float*)d_in[1];
    const float* w_gate = (const float*)d_in[2];
    const float* w_up   = (const float*)d_in[3];
    const float* w_down = (const float*)d_in[4];
    float* out = (float*)d_out;                    // final [T,H] ++ logits [T,E]
    float* logits_out = out + (size_t)T_TOK * HID;

    char* ws = (char*)d_ws;
    int*   counts    = (int*)(ws + 0);
    int*   cursor    = (int*)(ws + 32);
    int*   offsets   = (int*)(ws + 64);
    int*   topk_idx  = (int*)(ws + 256);
    float* topk_w    = (float*)(ws + 256 + 65536);
    int*   row_token = (int*)(ws + 256 + 2 * 65536);
    float* row_w     = (float*)(ws + 256 + 3 * 65536);
    int*   tok_rows  = (int*)(ws + 256 + 4 * 65536);
    int*   wl        = (int*)(ws + 256 + 5 * 65536);          // in slack region
    int*   n_wl      = (int*)(ws + 256 + 5 * 65536 + 2048);
    size_t o = 256 + 5 * (size_t)65536 + 65280;
    unsigned short* xb   = (unsigned short*)(ws + o); o += (size_t)T_TOK * HID * 2;
    unsigned short* wg_t = (unsigned short*)(ws + o); o += (size_t)NE * INTER * HID * 2;
    unsigned short* wu_t = (unsigned short*)(ws + o); o += (size_t)NE * INTER * HID * 2;
    unsigned short* wd_t = (unsigned short*)(ws + o); o += (size_t)NE * HID * INTER * 2;
    unsigned short* h_buf = (unsigned short*)(ws + o); o += (size_t)NROWS * INTER * 2;
    unsigned short* y_buf = (unsigned short*)(ws + o); o += (size_t)NROWS * HID * 2;

    moe_zero_meta<<<1, 64, 0, stream>>>(counts, cursor);
    moe_router<<<T_TOK / 4, 256, 0, stream>>>(x, gate_w, xb, logits_out,
                                              topk_idx, topk_w, counts);
    moe_scan<<<1, 64, 0, stream>>>(counts, offsets, wl, n_wl);
    moe_scatter<<<T_TOK / 256, 256, 0, stream>>>(topk_idx, topk_w, offsets, cursor,
                                                 row_token, row_w, tok_rows);
    dim3 tb(32, 8, 1);
    moe_transpose_cast<<<dim3(INTER / 32, HID / 32, NE), tb, 0, stream>>>(w_gate, wg_t, HID, INTER);
    moe_transpose_cast<<<dim3(INTER / 32, HID / 32, NE), tb, 0, stream>>>(w_up,   wu_t, HID, INTER);
    moe_transpose_cast<<<dim3(HID / 32, INTER / 32, NE), tb, 0, stream>>>(w_down, wd_t, INTER, HID);

    moe_gemm1<<<dim3(INTER / 64, MAXWL), 256, 0, stream>>>(
        xb, wg_t, wu_t, offsets, row_token, wl, n_wl, h_buf);
    moe_gemm2<<<dim3(HID / 128, MAXWL), 256, 0, stream>>>(
        h_buf, wd_t, offsets, row_w, wl, n_wl, y_buf);
    moe_combine<<<(T_TOK * HID / 8) / 256, 256, 0, stream>>>(y_buf, tok_rows, out);
}

// Round 4
// 470.747 us; speedup vs baseline: 1.8469x; 1.5391x over previous
//
#include <hip/hip_runtime.h>
#include <hip/hip_bf16.h>
#include <math.h>

// Problem constants (from reference)
#define T_TOK 8192            // B*S = 4*2048
#define HID   1024
#define NE    8
#define TOPKN 2
#define INTER 1408
#define NROWS (T_TOK*TOPKN)   // 16384 routed (token,expert) rows
#define MAXWL 144             // max row-block worklist entries
#define RBLK  256             // router blocks (32 tokens each)

typedef __attribute__((ext_vector_type(8))) __bf16 bf16x8;
typedef __attribute__((ext_vector_type(4))) float f32x4;
typedef __attribute__((ext_vector_type(4))) unsigned int u32x4;

__device__ __forceinline__ unsigned short f2bf(float f) {
    unsigned int u = __builtin_bit_cast(unsigned int, f);
    unsigned int lsb = (u >> 16) & 1u;
    u += 0x7fffu + lsb;            // round-to-nearest-even
    return (unsigned short)(u >> 16);
}

// async global->LDS, 16B per lane (m97 pattern).
__device__ __forceinline__ void gl2lds16(const void* g, void* l) {
    __builtin_amdgcn_global_load_lds(
        (const __attribute__((address_space(1))) unsigned int*)g,
        (__attribute__((address_space(3))) unsigned int*)l, 16, 0, 0);
}

// ---------------------------------------------------------------- router
// 32 tokens/block, wave-per-token x8. fp32 logits (exact top-k vs ref),
// x -> bf16 cast, per-block expert histogram (LDS atomics only, no global).
__global__ __launch_bounds__(256) void moe_router(
    const float* __restrict__ x, const float* __restrict__ gate_w,
    unsigned short* __restrict__ xb, float* __restrict__ logits_out,
    int* __restrict__ topk_idx, float* __restrict__ topk_w,
    int* __restrict__ hist_g)
{
    __shared__ int lh[NE];
    int tid = threadIdx.x, wave = tid >> 6, lane = tid & 63;
    if (tid < NE) lh[tid] = 0;
    __syncthreads();

#pragma unroll 1
    for (int i = 0; i < 8; i++) {
        int t = blockIdx.x * 32 + wave * 8 + i;
        const float4* xr = (const float4*)(x + (size_t)t * HID);
        float acc[NE];
#pragma unroll
        for (int e = 0; e < NE; e++) acc[e] = 0.f;
#pragma unroll
        for (int j = 0; j < 4; j++) {
            float4 xv = xr[j * 64 + lane];
            ushort4 pk;
            pk.x = f2bf(xv.x); pk.y = f2bf(xv.y);
            pk.z = f2bf(xv.z); pk.w = f2bf(xv.w);
            *(ushort4*)(xb + (size_t)t * HID + j * 256 + lane * 4) = pk;
#pragma unroll
            for (int e = 0; e < NE; e++) {
                float4 gv = *(const float4*)(gate_w + e * HID + j * 256 + lane * 4);
                acc[e] += xv.x * gv.x + xv.y * gv.y + xv.z * gv.z + xv.w * gv.w;
            }
        }
#pragma unroll
        for (int e = 0; e < NE; e++) {
            float v = acc[e];
#pragma unroll
            for (int off = 32; off; off >>= 1) v += __shfl_xor(v, off, 64);
            acc[e] = v;
        }
        if (lane == 0) {
            float m = acc[0];
#pragma unroll
            for (int e = 1; e < NE; e++) m = fmaxf(m, acc[e]);
            float p[NE]; float s = 0.f;
#pragma unroll
            for (int e = 0; e < NE; e++) { p[e] = expf(acc[e] - m); s += p[e]; }
            float inv = 1.f / s;
#pragma unroll
            for (int e = 0; e < NE; e++) logits_out[(size_t)t * NE + e] = acc[e];
            int i0 = 0;
#pragma unroll
            for (int e = 1; e < NE; e++) if (p[e] > p[i0]) i0 = e;
            int i1 = (i0 == 0) ? 1 : 0;
#pragma unroll
            for (int e = 0; e < NE; e++) if (e != i0 && p[e] > p[i1]) i1 = e;
            topk_idx[2 * t]     = i0; topk_w[2 * t]     = p[i0] * inv;
            topk_idx[2 * t + 1] = i1; topk_w[2 * t + 1] = p[i1] * inv;
            atomicAdd(&lh[i0], 1);
            atomicAdd(&lh[i1], 1);
        }
    }
    __syncthreads();
    if (tid < NE) hist_g[blockIdx.x * NE + tid] = lh[tid];
}

// ---------------------------------------------------------------- scan
// One block: expert totals, offsets, per-router-block bases, worklist.
__global__ __launch_bounds__(256) void moe_scan(
    const int* __restrict__ hist_g, int* __restrict__ offsets,
    int* __restrict__ block_base, int* __restrict__ wl, int* __restrict__ n_wl)
{
    __shared__ int h[RBLK * NE];
    __shared__ int cnt[NE], offs[NE];
    int tid = threadIdx.x;
    for (int i = tid; i < RBLK * NE; i += 256) h[i] = hist_g[i];
    __syncthreads();
    if (tid < NE) {
        int s = 0;
        for (int b = 0; b < RBLK; b++) s += h[b * NE + tid];
        cnt[tid] = s;
    }
    __syncthreads();
    if (tid == 0) {
        int s = 0;
        for (int e = 0; e < NE; e++) { offs[e] = s; offsets[e] = s; s += cnt[e]; }
        offsets[NE] = s;
        int n = 0;
        for (int e = 0; e < NE; e++)
            for (int r0 = 0; r0 < cnt[e]; r0 += 128)
                wl[n++] = (e << 24) | r0;
        *n_wl = n;
    }
    __syncthreads();
    if (tid < NE) {
        int run = offs[tid];
        for (int b = 0; b < RBLK; b++) {
            block_base[b * NE + tid] = run;
            run += h[b * NE + tid];
        }
    }
}

// ---------------------------------------------------------------- scatter
// 64 entries (32 tokens x 2) per block; LDS cursors seeded from block_base.
// Zero global atomics. Rank within expert bucket arbitrary (order-neutral).
__global__ __launch_bounds__(64) void moe_scatter(
    const int* __restrict__ topk_idx, const float* __restrict__ topk_w,
    const int* __restrict__ block_base, int* __restrict__ row_token,
    float* __restrict__ row_w, int* __restrict__ tok_rows)
{
    __shared__ int base[NE];
    int tid = threadIdx.x;
    if (tid < NE) base[tid] = block_base[blockIdx.x * NE + tid];
    __syncthreads();
    int idx = blockIdx.x * 64 + tid;     // = 2*t + k
    int e = topk_idx[idx];
    int pos = atomicAdd(&base[e], 1);    // LDS atomic
    row_token[pos] = idx >> 1;
    row_w[pos] = topk_w[idx];
    tok_rows[idx] = pos;
}

// ---------------------------------------------------------------- transpose+cast
// in: fp32 [NE][R_][C_]  ->  out: bf16 [NE][C_][R_]   (k-contiguous weights)
__global__ __launch_bounds__(256) void moe_transpose_cast(
    const float* __restrict__ in, unsigned short* __restrict__ out,
    int R_, int C_)
{
    __shared__ float tile[32][33];
    int e = blockIdx.z;
    const float* ine = in + (size_t)e * R_ * C_;
    unsigned short* oute = out + (size_t)e * R_ * C_;
    int c0 = blockIdx.x * 32, r0 = blockIdx.y * 32;
    int tx = threadIdx.x, ty = threadIdx.y;     // (32,8)
#pragma unroll
    for (int j = 0; j < 4; j++) {
        int r = r0 + ty + j * 8;
        tile[ty + j * 8][tx] = ine[(size_t)r * C_ + c0 + tx];
    }
    __syncthreads();
#pragma unroll
    for (int j = 0; j < 4; j++) {
        int c = c0 + ty + j * 8;
        oute[(size_t)c * R_ + r0 + tx] = f2bf(tile[tx][ty + j * 8]);
    }
}

// ---------------------------------------------------------------- grouped GEMM1
// 128 rows x 64 i-cols per block, computes BOTH g and u (SiLU pairing wave-local).
// LDS row-major [row][chunk], chunk c of row r holds logical k-chunk q = c^(r&7)
// (XOR swizzle): staging lane-contiguous AND coalesced; frag reads 2-way (free).
__global__ __launch_bounds__(256) void moe_gemm1(
    const unsigned short* __restrict__ xb,
    const unsigned short* __restrict__ wg_t,   // [NE][INTER][HID]
    const unsigned short* __restrict__ wu_t,   // [NE][INTER][HID]
    const int* __restrict__ offsets, const int* __restrict__ row_token,
    const int* __restrict__ wl, const int* __restrict__ n_wl,
    unsigned short* __restrict__ h_buf)        // [NROWS][INTER]
{
    if ((int)blockIdx.y >= *n_wl) return;
    int wle = wl[blockIdx.y];
    int e = wle >> 24, row0 = wle & 0xffffff;
    int off = offsets[e], cnt = offsets[e + 1] - off;
    int i0 = blockIdx.x * 64;

    __shared__ __align__(16) unsigned short As[128 * 64];  // 16 KB: [row][8 chunks]
    __shared__ __align__(16) unsigned short Bg[64 * 64];   // 8 KB
    __shared__ __align__(16) unsigned short Bu[64 * 64];   // 8 KB

    int tid = threadIdx.x, wave = tid >> 6, lane = tid & 63;
    int wm = wave & 1, wn = wave >> 1;
    int l16 = lane & 15, quad = lane >> 4;
    int r_ = lane >> 3, c_ = lane & 7;     // staging: 8 rows x 8 chunks per wave-instr
    int sw = l16 & 7;                      // frag-read xor swizzle

    const unsigned short* asrc[4];
#pragma unroll
    for (int it = 0; it < 4; it++) {
        int rloc = it * 32 + wave * 8 + r_;
        int rg = row0 + rloc;
        int tok = row_token[off + ((rg < cnt) ? rg : 0)];
        asrc[it] = xb + (size_t)tok * HID + (c_ ^ (rloc & 7)) * 8;
    }
    const unsigned short* bgsrc[2];
    const unsigned short* busrc[2];
#pragma unroll
    for (int it = 0; it < 2; it++) {
        int rloc = it * 32 + wave * 8 + r_;
        size_t boff = (size_t)e * INTER * HID + (size_t)(i0 + rloc) * HID + (c_ ^ (rloc & 7)) * 8;
        bgsrc[it] = wg_t + boff;
        busrc[it] = wu_t + boff;
    }

    f32x4 accg[4][2], accu[4][2];
#pragma unroll
    for (int mi = 0; mi < 4; mi++)
#pragma unroll
        for (int ni = 0; ni < 2; ni++) {
            accg[mi][ni] = {0.f, 0.f, 0.f, 0.f};
            accu[mi][ni] = {0.f, 0.f, 0.f, 0.f};
        }

    for (int k0 = 0; k0 < HID; k0 += 64) {
#pragma unroll
        for (int it = 0; it < 4; it++)
            gl2lds16(asrc[it] + k0, &As[(it * 32 + wave * 8) * 64]);
#pragma unroll
        for (int it = 0; it < 2; it++) {
            gl2lds16(bgsrc[it] + k0, &Bg[(it * 32 + wave * 8) * 64]);
            gl2lds16(busrc[it] + k0, &Bu[(it * 32 + wave * 8) * 64]);
        }
        __syncthreads();
#pragma unroll
        for (int kk8 = 0; kk8 < 8; kk8 += 4) {
            int q = kk8 + quad;
            int qs = (q ^ sw) * 8;
            bf16x8 a[4], bg[2], bu[2];
#pragma unroll
            for (int mi = 0; mi < 4; mi++)
                a[mi] = *(const bf16x8*)&As[(wm * 64 + mi * 16 + l16) * 64 + qs];
#pragma unroll
            for (int ni = 0; ni < 2; ni++) {
                bg[ni] = *(const bf16x8*)&Bg[(wn * 32 + ni * 16 + l16) * 64 + qs];
                bu[ni] = *(const bf16x8*)&Bu[(wn * 32 + ni * 16 + l16) * 64 + qs];
            }
#pragma unroll
            for (int mi = 0; mi < 4; mi++)
#pragma unroll
                for (int ni = 0; ni < 2; ni++) {
                    accg[mi][ni] = __builtin_amdgcn_mfma_f32_16x16x32_bf16(a[mi], bg[ni], accg[mi][ni], 0, 0, 0);
                    accu[mi][ni] = __builtin_amdgcn_mfma_f32_16x16x32_bf16(a[mi], bu[ni], accu[mi][ni], 0, 0, 0);
                }
        }
        __syncthreads();
    }
    // epilogue: silu(g)*u -> bf16  (C/D: col=lane&15, row=quad*4+reg)
#pragma unroll
    for (int mi = 0; mi < 4; mi++)
#pragma unroll
        for (int ni = 0; ni < 2; ni++)
#pragma unroll
            for (int r = 0; r < 4; r++) {
                int ml = wm * 64 + mi * 16 + quad * 4 + r;
                int row = row0 + ml;
                if (row < cnt) {
                    float g = accg[mi][ni][r], u = accu[mi][ni][r];
                    float hv = (g / (1.f + expf(-g))) * u;
                    h_buf[(size_t)(off + row) * INTER + i0 + wn * 32 + ni * 16 + l16] = f2bf(hv);
                }
            }
}

// ---------------------------------------------------------------- grouped GEMM2
// m97-style 128x128, per-wave 64x64, same XOR-swizzle staging.
__global__ __launch_bounds__(256) void moe_gemm2(
    const unsigned short* __restrict__ h_buf,  // [NROWS][INTER]
    const unsigned short* __restrict__ wd_t,   // [NE][HID][INTER]
    const int* __restrict__ offsets, const float* __restrict__ row_w,
    const int* __restrict__ wl, const int* __restrict__ n_wl,
    unsigned short* __restrict__ y_buf)        // [NROWS][HID]
{
    if ((int)blockIdx.y >= *n_wl) return;
    int wle = wl[blockIdx.y];
    int e = wle >> 24, row0 = wle & 0xffffff;
    int off = offsets[e], cnt = offsets[e + 1] - off;
    int h0 = blockIdx.x * 128;

    __shared__ __align__(16) unsigned short As[128 * 64];  // 16 KB
    __shared__ __align__(16) unsigned short Bs[128 * 64];  // 16 KB

    int tid = threadIdx.x, wave = tid >> 6, lane = tid & 63;
    int wm = wave & 1, wn = wave >> 1;
    int l16 = lane & 15, quad = lane >> 4;
    int r_ = lane >> 3, c_ = lane & 7;
    int sw = l16 & 7;

    const unsigned short* asrc[4];
    const unsigned short* bsrc[4];
#pragma unroll
    for (int it = 0; it < 4; it++) {
        int rloc = it * 32 + wave * 8 + r_;
        int rg = row0 + rloc;
        asrc[it] = h_buf + (size_t)(off + ((rg < cnt) ? rg : 0)) * INTER + (c_ ^ (rloc & 7)) * 8;
        bsrc[it] = wd_t + (size_t)e * HID * INTER + (size_t)(h0 + rloc) * INTER + (c_ ^ (rloc & 7)) * 8;
    }

    f32x4 acc[4][4];
#pragma unroll
    for (int mi = 0; mi < 4; mi++)
#pragma unroll
        for (int ni = 0; ni < 4; ni++) acc[mi][ni] = {0.f, 0.f, 0.f, 0.f};

    for (int k0 = 0; k0 < INTER; k0 += 64) {
#pragma unroll
        for (int it = 0; it < 4; it++) {
            gl2lds16(asrc[it] + k0, &As[(it * 32 + wave * 8) * 64]);
            gl2lds16(bsrc[it] + k0, &Bs[(it * 32 + wave * 8) * 64]);
        }
        __syncthreads();
#pragma unroll
        for (int kk8 = 0; kk8 < 8; kk8 += 4) {
            int q = kk8 + quad;
            int qs = (q ^ sw) * 8;
            bf16x8 a[4], b[4];
#pragma unroll
            for (int mi = 0; mi < 4; mi++)
                a[mi] = *(const bf16x8*)&As[(wm * 64 + mi * 16 + l16) * 64 + qs];
#pragma unroll
            for (int ni = 0; ni < 4; ni++)
                b[ni] = *(const bf16x8*)&Bs[(wn * 64 + ni * 16 + l16) * 64 + qs];
#pragma unroll
            for (int mi = 0; mi < 4; mi++)
#pragma unroll
                for (int ni = 0; ni < 4; ni++)
                    acc[mi][ni] = __builtin_amdgcn_mfma_f32_16x16x32_bf16(a[mi], b[ni], acc[mi][ni], 0, 0, 0);
        }
        __syncthreads();
    }
#pragma unroll
    for (int mi = 0; mi < 4; mi++)
#pragma unroll
        for (int ni = 0; ni < 4; ni++)
#pragma unroll
            for (int r = 0; r < 4; r++) {
                int ml = wm * 64 + mi * 16 + quad * 4 + r;
                int row = row0 + ml;
                if (row < cnt) {
                    float w = row_w[off + row];
                    y_buf[(size_t)(off + row) * HID + h0 + wn * 64 + ni * 16 + l16] =
                        f2bf(acc[mi][ni][r] * w);
                }
            }
}

// ---------------------------------------------------------------- combine
__global__ __launch_bounds__(256) void moe_combine(
    const unsigned short* __restrict__ y_buf, const int* __restrict__ tok_rows,
    float* __restrict__ out)
{
    int gid = blockIdx.x * 256 + threadIdx.x;   // T*H/8 threads
    int t = gid >> 7;
    int c = gid & 127;
    u32x4 a = *(const u32x4*)(y_buf + (size_t)tok_rows[2 * t]     * HID + c * 8);
    u32x4 b = *(const u32x4*)(y_buf + (size_t)tok_rows[2 * t + 1] * HID + c * 8);
    float res[8];
#pragma unroll
    for (int j = 0; j < 4; j++) {
        unsigned int wa = a[j], wb = b[j];
        res[2 * j]     = __builtin_bit_cast(float, wa << 16)
                       + __builtin_bit_cast(float, wb << 16);
        res[2 * j + 1] = __builtin_bit_cast(float, wa & 0xffff0000u)
                       + __builtin_bit_cast(float, wb & 0xffff0000u);
    }
    float* o = out + (size_t)t * HID + c * 8;
    *(float4*)(o)     = make_float4(res[0], res[1], res[2], res[3]);
    *(float4*)(o + 4) = make_float4(res[4], res[5], res[6], res[7]);
}

// ---------------------------------------------------------------- launch
extern "C" void kernel_launch(void* const* d_in, const int* in_sizes, int n_in,
                              void* d_out, int out_size, void* d_ws, size_t ws_size,
                              hipStream_t stream)
{
    const float* x      = (const float*)d_in[0];
    const float* gate_w = (const float*)d_in[1];
    const float* w_gate = (const float*)d_in[2];
    const float* w_up   = (const float*)d_in[3];
    const float* w_down = (const float*)d_in[4];
    float* out = (float*)d_out;                    // final [T,H] ++ logits [T,E]
    float* logits_out = out + (size_t)T_TOK * HID;

    char* ws = (char*)d_ws;
    int*   offsets    = (int*)(ws + 0);                  // 9 ints
    int*   n_wl       = (int*)(ws + 64);
    int*   wl         = (int*)(ws + 128);                // MAXWL ints
    int*   hist_g     = (int*)(ws + 1024);               // RBLK*NE = 8 KB
    int*   block_base = (int*)(ws + 1024 + 8192);        // 8 KB
    int*   topk_idx   = (int*)(ws + 32768);                       // 64 KB
    float* topk_w     = (float*)(ws + 32768 + 65536);             // 64 KB
    int*   row_token  = (int*)(ws + 32768 + 2 * 65536);           // 64 KB
    float* row_w      = (float*)(ws + 32768 + 3 * 65536);         // 64 KB
    int*   tok_rows   = (int*)(ws + 32768 + 4 * 65536);           // 64 KB
    size_t o = 32768 + 5 * (size_t)65536 + 32768;        // 393216
    unsigned short* xb   = (unsigned short*)(ws + o); o += (size_t)T_TOK * HID * 2;
    unsigned short* wg_t = (unsigned short*)(ws + o); o += (size_t)NE * INTER * HID * 2;
    unsigned short* wu_t = (unsigned short*)(ws + o); o += (size_t)NE * INTER * HID * 2;
    unsigned short* wd_t = (unsigned short*)(ws + o); o += (size_t)NE * HID * INTER * 2;
    unsigned short* h_buf = (unsigned short*)(ws + o); o += (size_t)NROWS * INTER * 2;
    unsigned short* y_buf = (unsigned short*)(ws + o); o += (size_t)NROWS * HID * 2;

    moe_router<<<RBLK, 256, 0, stream>>>(x, gate_w, xb, logits_out,
                                         topk_idx, topk_w, hist_g);
    moe_scan<<<1, 256, 0, stream>>>(hist_g, offsets, block_base, wl, n_wl);
    moe_scatter<<<RBLK, 64, 0, stream>>>(topk_idx, topk_w, block_base,
                                         row_token, row_w, tok_rows);
    dim3 tb(32, 8, 1);
    moe_transpose_cast<<<dim3(INTER / 32, HID / 32, NE), tb, 0, stream>>>(w_gate, wg_t, HID, INTER);
    moe_transpose_cast<<<dim3(INTER / 32, HID / 32, NE), tb, 0, stream>>>(w_up,   wu_t, HID, INTER);
    moe_transpose_cast<<<dim3(HID / 32, INTER / 32, NE), tb, 0, stream>>>(w_down, wd_t, INTER, HID);

    moe_gemm1<<<dim3(INTER / 64, MAXWL), 256, 0, stream>>>(
        xb, wg_t, wu_t, offsets, row_token, wl, n_wl, h_buf);
    moe_gemm2<<<dim3(HID / 128, MAXWL), 256, 0, stream>>>(
        h_buf, wd_t, offsets, row_w, wl, n_wl, y_buf);
    moe_combine<<<(T_TOK * HID / 8) / 256, 256, 0, stream>>>(y_buf, tok_rows, out);
}